// Round 6
// baseline (375.623 us; speedup 1.0000x reference)
//
#include <hip/hip_runtime.h>

// ---------------- problem constants ----------------
#define B_    2
#define Q_    2048
#define HID_  2048
#define HQ_   16
#define HKV_  4
#define D_    128
// softmax scale folded into q, in exp2 domain: D^-0.5 * log2(e)
#define QSC_  (0.08838834764831843f * 1.4426950408889634f)
#define LOG2_THETA 19.931568569324174f // log2(1e6)
// fixed softmax max: |score*log2e| <= sqrt(128)*1.4427 = 16.33 < 20 (RMSNorm'd q,k)
#define FMAX_ 20.0f

typedef unsigned short u16;
typedef __attribute__((ext_vector_type(8))) short bf16x8;
typedef __attribute__((ext_vector_type(4))) float f32x4;

__device__ __forceinline__ u16 f2bf(float x) {           // round-nearest-even
  union { float f; unsigned int u; } v; v.f = x;
  unsigned int r = v.u + 0x7FFFu + ((v.u >> 16) & 1u);
  return (u16)(r >> 16);
}
__device__ __forceinline__ u16 f2bf_t(float x) {         // truncate (hot loop)
  union { float f; unsigned int u; } v; v.f = x;
  return (u16)(v.u >> 16);
}

// async global->LDS, 16B per lane; lds must be the wave-uniform base
__device__ __forceinline__ void gl2lds16(u16* lds, const u16* g) {
  __builtin_amdgcn_global_load_lds((const __attribute__((address_space(1))) void*)g,
                                   (__attribute__((address_space(3))) void*)lds,
                                   16, 0, 0);
}

// ------- fused fp32->bf16 casts (hidden, wqkv, wo) + RoPE cos/sin table -----
// wqkv q/k head rows are PERMUTED on store: within each head, dest row
// j = d with bits 5 and 6 swapped. This makes RoPE pairs (d, d+64) land
// in-lane (ni, ni+2) under the 2x2 GEMM wave mapping.
#define N4_HID  2097152
#define N4_WQKV 1572864
#define N4_WO   1048576
#define N4_ALL  (N4_HID + N4_WQKV + N4_WO)     // 4718592 = 18432*256
#define NROPE   (B_ * Q_ * 64)                 // 262144  = 1024*256
__global__ __launch_bounds__(256) void cvt_all(const float* __restrict__ h,
                                               const float* __restrict__ wq,
                                               const float* __restrict__ wo,
                                               const int* __restrict__ pos,
                                               u16* __restrict__ oh,
                                               u16* __restrict__ owq,
                                               u16* __restrict__ owo,
                                               float* __restrict__ rope) {
  int i = blockIdx.x * 256 + threadIdx.x;
  if (i >= N4_ALL) {                            // RoPE table part
    int j = i - N4_ALL;                         // < NROPE
    int d = j & 63, row = j >> 6;
    float p = (float)pos[row];
    float inv = exp2f(-(float)d * (LOG2_THETA / 64.f));
    float sn, cn;
    sincosf(p * inv, &sn, &cn);
    ((float2*)rope)[j] = make_float2(cn, sn);
    return;
  }
  if (i < N4_HID) {
    float4 v = *(const float4*)(h + (size_t)i * 4);
    ushort4 o;
    o.x = f2bf(v.x); o.y = f2bf(v.y); o.z = f2bf(v.z); o.w = f2bf(v.w);
    *(ushort4*)(oh + (size_t)i * 4) = o;
  } else if (i < N4_HID + N4_WQKV) {
    int off = i - N4_HID;
    float4 v = *(const float4*)(wq + (size_t)off * 4);
    int row = off >> 9;                         // 512 float4 per 2048-row
    int dst_row = row;
    if (row < 2560) {                           // q/k heads: swap bits 5,6 of d
      int d = row & 127;
      int j = (d & 31) | ((d >> 1) & 32) | ((d & 32) << 1);
      dst_row = (row & ~127) | j;
    }
    size_t doff = ((size_t)dst_row << 9) | (off & 511);
    ushort4 o;
    o.x = f2bf(v.x); o.y = f2bf(v.y); o.z = f2bf(v.z); o.w = f2bf(v.w);
    *(ushort4*)(owq + doff * 4) = o;
  } else {
    int off = i - N4_HID - N4_WQKV;
    float4 v = *(const float4*)(wo + (size_t)off * 4);
    ushort4 o;
    o.x = f2bf(v.x); o.y = f2bf(v.y); o.z = f2bf(v.z); o.w = f2bf(v.w);
    *(ushort4*)(owo + (size_t)off * 4) = o;
  }
}

// ---------------- fused QKV GEMM + RMSNorm + RoPE + layout ------------------
// 2x2 wave mapping (identical K-loop to gemm_bt: 8 ds_read_b128/k-step).
// Column permutation (bits 5<->6 of d, applied to wqkv in cvt_all) makes
// RoPE pairs in-lane: lane col ni pairs with ni+2; original
// d1 = wn*32 + pn*16 + c (pn=0,1), pair = d1 + 64.
// RMSNorm cross-wn combine via 1KB LDS float table.
__global__ __launch_bounds__(256) void gemm_qkv(const u16* __restrict__ A,
                                                const u16* __restrict__ Bw,
                                                const float* __restrict__ rope,
                                                const float* __restrict__ qw,
                                                const float* __restrict__ kw,
                                                u16* __restrict__ qb,
                                                u16* __restrict__ kb,
                                                u16* __restrict__ vt) {
  __shared__ __align__(16) u16 lds[12288];    // staging 16KB; epilogue reuses
  u16* As = lds;
  u16* Bs = lds + 4096;
  const int tid = threadIdx.x;
  const int wv = tid >> 6, lane = tid & 63;
  const int wm = wv & 1, wn = wv >> 1;
  const int c = lane & 15, quad = lane >> 4;
  const int lr = lane >> 2, lp = lane & 3;
  const int lpg = (lp + 4 - ((lr >> 1) & 3)) & 3;          // staging swizzle
  const int swq = ((quad + (c >> 1)) & 3) * 8;             // read swizzle
  const int m0 = blockIdx.x * 128;
  const int by = blockIdx.y;
  const int n0 = by * 128;
  f32x4 acc[4][4] = {};
  for (int k0 = 0; k0 < HID_; k0 += 32) {
    __syncthreads();
#pragma unroll
    for (int i = 0; i < 2; i++) {
      int r = wv * 16 + i * 64 + lr;
      gl2lds16(As + (size_t)(wv * 64 + i * 256) * 8,
               A + (size_t)(m0 + r) * HID_ + k0 + lpg * 8);
      gl2lds16(Bs + (size_t)(wv * 64 + i * 256) * 8,
               Bw + (size_t)(n0 + r) * HID_ + k0 + lpg * 8);
    }
    __syncthreads();
    bf16x8 af[4], bfr[4];
#pragma unroll
    for (int t = 0; t < 4; t++) {
      af[t]  = *(const bf16x8*)(As + (wm * 64 + t * 16 + c) * 32 + swq);
      bfr[t] = *(const bf16x8*)(Bs + (wn * 64 + t * 16 + c) * 32 + swq);
    }
#pragma unroll
    for (int mi = 0; mi < 4; mi++)
#pragma unroll
      for (int ni = 0; ni < 4; ni++)
        acc[mi][ni] = __builtin_amdgcn_mfma_f32_16x16x32_bf16(af[mi], bfr[ni],
                                                              acc[mi][ni], 0, 0, 0);
  }
  __syncthreads();                  // staging reads done; LDS reusable

  if (by < 20) {
    // ---- q/k head: RMSNorm (cross-wn via LDS) + RoPE (in-lane) ----
    const bool isq = by < 16;
    const float* w = isq ? qw : kw;
    const float osc = isq ? QSC_ : 1.f;
    // partial sum of squares over this wave's 64 cols, per row
    float ssp[4][4];
#pragma unroll
    for (int mi = 0; mi < 4; mi++)
#pragma unroll
      for (int r = 0; r < 4; r++) {
        float s = 0.f;
#pragma unroll
        for (int ni = 0; ni < 4; ni++) s += acc[mi][ni][r] * acc[mi][ni][r];
        s += __shfl_xor(s, 1); s += __shfl_xor(s, 2);
        s += __shfl_xor(s, 4); s += __shfl_xor(s, 8);
        ssp[mi][r] = s;
      }
    float* fss = (float*)(lds + 8704);          // [row128][wn] floats
    if (c == 0) {
#pragma unroll
      for (int mi = 0; mi < 4; mi++)
#pragma unroll
        for (int r = 0; r < 4; r++)
          fss[(wm * 64 + mi * 16 + quad * 4 + r) * 2 + wn] = ssp[mi][r];
    }
    __syncthreads();
    float rn[4][4];
#pragma unroll
    for (int mi = 0; mi < 4; mi++)
#pragma unroll
      for (int r = 0; r < 4; r++) {
        float2 both = ((const float2*)fss)[wm * 64 + mi * 16 + quad * 4 + r];
        rn[mi][r] = rsqrtf((both.x + both.y) * (1.f / 128.f) + 1e-6f) * osc;
      }
    float w1[2], w2[2];
#pragma unroll
    for (int pn = 0; pn < 2; pn++) {
      w1[pn] = w[wn * 32 + pn * 16 + c];
      w2[pn] = w[64 + wn * 32 + pn * 16 + c];
    }
    u16* dstbuf = isq ? qb : kb;
    const int hbase = isq ? by : (by - 16);
    const int nheads = isq ? HQ_ : HKV_;
#pragma unroll
    for (int ph = 0; ph < 2; ph++) {
      if (ph) __syncthreads();
      if (wm == ph) {
#pragma unroll
        for (int mi = 0; mi < 4; mi++)
#pragma unroll
          for (int r = 0; r < 4; r++) {
            const int rl = mi * 16 + quad * 4 + r;
            const int rowg = m0 + ph * 64 + rl;
            const int q = rowg & (Q_ - 1), b = rowg >> 11;
            const float* rp = rope + ((size_t)(b * Q_ + q) * 64) * 2;
            u16* lrow = lds + rl * 132;
#pragma unroll
            for (int pn = 0; pn < 2; pn++) {
              const int d1 = wn * 32 + pn * 16 + c;
              float2 cs = *(const float2*)(rp + d1 * 2);
              float x1 = acc[mi][pn][r]     * w1[pn] * rn[mi][r];
              float x2 = acc[mi][pn + 2][r] * w2[pn] * rn[mi][r];
              lrow[d1]      = f2bf(x1 * cs.x - x2 * cs.y);
              lrow[d1 + 64] = f2bf(x2 * cs.x + x1 * cs.y);
            }
          }
      }
      __syncthreads();
      const int rowg = m0 + ph * 64 + (tid >> 2);
      const int q = rowg & (Q_ - 1), b = rowg >> 11;
      u16* dst = dstbuf + (((size_t)(b * nheads) + hbase) * Q_ + q) * D_ + (tid & 3) * 32;
      const u16* srcl = lds + (tid >> 2) * 132 + (tid & 3) * 32;
#pragma unroll
      for (int j = 0; j < 4; j++)
        *(bf16x8*)(dst + j * 8) = *(const bf16x8*)(srcl + j * 8);
    }
  } else {
    // ---- v head: transpose to (B,HKV,D,S); phases over d-halves (wn) ----
    const int hk = by - 20;
    const int bb = m0 >> 11, q0 = m0 & (Q_ - 1);
#pragma unroll
    for (int ph = 0; ph < 2; ph++) {
      if (ph) __syncthreads();
      if (wn == ph) {
#pragma unroll
        for (int mi = 0; mi < 4; mi++)
#pragma unroll
          for (int ni = 0; ni < 4; ni++) {
            short4 pv;
            pv.x = (short)f2bf(acc[mi][ni][0]); pv.y = (short)f2bf(acc[mi][ni][1]);
            pv.z = (short)f2bf(acc[mi][ni][2]); pv.w = (short)f2bf(acc[mi][ni][3]);
            *(short4*)(lds + (ni * 16 + c) * 132 + wm * 64 + mi * 16 + quad * 4) = pv;
          }
      }
      __syncthreads();
      const int dl = tid >> 2;
      u16* dst = vt + (((size_t)(bb * HKV_) + hk) * D_ + ph * 64 + dl) * Q_ +
                 q0 + (tid & 3) * 32;
      const u16* srcl = lds + dl * 132 + (tid & 3) * 32;
#pragma unroll
      for (int j = 0; j < 4; j++)
        *(bf16x8*)(dst + j * 8) = *(const bf16x8*)(srcl + j * 8);
    }
  }
}

// ---------------- bf16 GEMM, C = A * B^T (A: MxK, B: NxK, C: MxN fp32) ------
__global__ __launch_bounds__(256) void gemm_bt(const u16* __restrict__ A,
                                               const u16* __restrict__ Bw,
                                               float* __restrict__ C,
                                               int M, int N, int K) {
  __shared__ __align__(16) u16 As[128 * 32];
  __shared__ __align__(16) u16 Bs[128 * 32];
  const int tid = threadIdx.x;
  const int wave = tid >> 6, lane = tid & 63;
  const int wm = wave & 1, wn = wave >> 1;
  const int row16 = lane & 15, quad = lane >> 4;
  const int lr = lane >> 2, lp = lane & 3;
  const int lpg = (lp + 4 - ((lr >> 1) & 3)) & 3;
  const int swq = ((quad + (row16 >> 1)) & 3) * 8;
  const int m0 = blockIdx.x * 128, n0 = blockIdx.y * 128;
  f32x4 acc[4][4] = {};
  for (int k0 = 0; k0 < K; k0 += 32) {
    __syncthreads();
#pragma unroll
    for (int i = 0; i < 2; i++) {
      int r = wave * 16 + i * 64 + lr;
      gl2lds16(As + (size_t)(wave * 64 + i * 256) * 8,
               A + (size_t)(m0 + r) * K + k0 + lpg * 8);
      gl2lds16(Bs + (size_t)(wave * 64 + i * 256) * 8,
               Bw + (size_t)(n0 + r) * K + k0 + lpg * 8);
    }
    __syncthreads();
    bf16x8 af[4], bfr[4];
#pragma unroll
    for (int t = 0; t < 4; t++) {
      af[t]  = *(const bf16x8*)(As + (wm * 64 + t * 16 + row16) * 32 + swq);
      bfr[t] = *(const bf16x8*)(Bs + (wn * 64 + t * 16 + row16) * 32 + swq);
    }
#pragma unroll
    for (int mi = 0; mi < 4; mi++)
#pragma unroll
      for (int ni = 0; ni < 4; ni++)
        acc[mi][ni] = __builtin_amdgcn_mfma_f32_16x16x32_bf16(af[mi], bfr[ni],
                                                              acc[mi][ni], 0, 0, 0);
  }
#pragma unroll
  for (int mi = 0; mi < 4; mi++) {
    int row = m0 + wm * 64 + mi * 16 + quad * 4;
#pragma unroll
    for (int ni = 0; ni < 4; ni++) {
      int col = n0 + wn * 64 + ni * 16 + row16;
#pragma unroll
      for (int r = 0; r < 4; r++)
        C[(size_t)(row + r) * N + col] = acc[mi][ni][r];
    }
  }
}

// ------ flash attention, causal, GQA; fixed-max softmax (RMSNorm bound) -----
__global__ __launch_bounds__(256) void attn_fwd(const u16* __restrict__ qb,
                                                const u16* __restrict__ kb,
                                                const u16* __restrict__ vt,
                                                u16* __restrict__ ob) {
  __shared__ __align__(16) u16 lds[8192 + 8192 + 4608];
  u16* Ks = lds;            // [kk 0..3][key 0..63][32]   (swizzled chunks)
  u16* Vs = lds + 8192;     // [kk2 0..1][d 0..127][32]   (swizzled chunks)
  u16* Ps = lds + 16384;    // per-wave [c 0..15][key 0..63], row stride 72
  const int p = blockIdx.x, h = blockIdx.y, b = blockIdx.z;
  const int hk = h >> 2;
  const int tid = threadIdx.x, wave = tid >> 6, lane = tid & 63;
  const int c = lane & 15, quad = lane >> 4;
  const int lr = lane >> 2, lp = lane & 3;
  const int lpg = (lp + 4 - ((lr >> 1) & 3)) & 3;
  const int swq = ((quad + (c >> 1)) & 3) * 8;
  const u16* qg = qb + ((size_t)b * HQ_ + h) * (size_t)Q_ * D_;
  const u16* kg = kb + ((size_t)b * HKV_ + hk) * (size_t)Q_ * D_;
  const u16* vg = vt + ((size_t)b * HKV_ + hk) * (size_t)D_ * Q_;
  u16* Pw = Ps + wave * 1152;
  u16* Bw = Ks + wave * 2176;

#pragma unroll 1
  for (int tp = 0; tp < 2; tp++) {
    const int t = tp ? (31 - p) : p;
    const int q0 = t * 64;
    const int qrow = q0 + wave * 16 + c;
    bf16x8 qf[4];
#pragma unroll
    for (int kk = 0; kk < 4; kk++)
      qf[kk] = *(const bf16x8*)(qg + (size_t)qrow * D_ + kk * 32 + quad * 8);
    f32x4 Oa[8] = {};
    float l_acc = 0.f;

#pragma unroll 1
    for (int kt = 0; kt <= t; kt++) {
      __syncthreads();
#pragma unroll
      for (int i = 0; i < 4; i++) {
        gl2lds16(Ks + (size_t)(i * 256 + wave * 64) * 8,
                 kg + ((size_t)kt * 64 + wave * 16 + lr) * D_ + i * 32 + lpg * 8);
        int d = (i & 1) * 64 + wave * 16 + lr;
        gl2lds16(Vs + (size_t)(i * 256 + wave * 64) * 8,
                 vg + (size_t)d * Q_ + kt * 64 + (i >> 1) * 32 + lpg * 8);
      }
      __syncthreads();
      f32x4 S[4];
#pragma unroll
      for (int n = 0; n < 4; n++) {
        f32x4 a = {-FMAX_, -FMAX_, -FMAX_, -FMAX_};   // bias folded into C
#pragma unroll
        for (int kk = 0; kk < 4; kk++) {
          bf16x8 kf = *(const bf16x8*)(Ks + kk * 2048 + (n * 16 + c) * 32 + swq);
          a = __builtin_amdgcn_mfma_f32_16x16x32_bf16(kf, qf[kk], a, 0, 0, 0);
        }
        S[n] = a;
      }
      if (kt == t) {
#pragma unroll
        for (int n = 0; n < 4; n++)
#pragma unroll
          for (int r = 0; r < 4; r++) {
            int key = kt * 64 + n * 16 + quad * 4 + r;
            if (key > qrow) S[n][r] = -1e9f;          // exp2 -> 0
          }
      }
#pragma unroll
      for (int n = 0; n < 4; n++) {
        float p0 = __builtin_amdgcn_exp2f(S[n][0]);
        float p1 = __builtin_amdgcn_exp2f(S[n][1]);
        float p2 = __builtin_amdgcn_exp2f(S[n][2]);
        float p3 = __builtin_amdgcn_exp2f(S[n][3]);
        l_acc += (p0 + p1) + (p2 + p3);
        short4 pk;
        pk.x = (short)f2bf_t(p0); pk.y = (short)f2bf_t(p1);
        pk.z = (short)f2bf_t(p2); pk.w = (short)f2bf_t(p3);
        *(short4*)(Pw + c * 72 + n * 16 + quad * 4) = pk;
      }
      bf16x8 pf[2];
#pragma unroll
      for (int kk2 = 0; kk2 < 2; kk2++)
        pf[kk2] = *(const bf16x8*)(Pw + c * 72 + kk2 * 32 + quad * 8);
#pragma unroll
      for (int md = 0; md < 8; md++)
#pragma unroll
        for (int kk2 = 0; kk2 < 2; kk2++) {
          bf16x8 vf = *(const bf16x8*)(Vs + kk2 * 4096 + (md * 16 + c) * 32 + swq);
          Oa[md] = __builtin_amdgcn_mfma_f32_16x16x32_bf16(vf, pf[kk2], Oa[md], 0, 0, 0);
        }
    }
    // strip epilogue: reduce l across quads, normalize, transpose, store
    float l_row = l_acc;
    l_row += __shfl_xor(l_row, 16);
    l_row += __shfl_xor(l_row, 32);
    __syncthreads();    // Ks/Vs now reusable as bounce space
    const float invl = 1.f / l_row;
#pragma unroll
    for (int md = 0; md < 8; md++) {
      short4 ok;
      ok.x = (short)f2bf(Oa[md][0] * invl); ok.y = (short)f2bf(Oa[md][1] * invl);
      ok.z = (short)f2bf(Oa[md][2] * invl); ok.w = (short)f2bf(Oa[md][3] * invl);
      *(short4*)(Bw + c * 136 + md * 16 + quad * 4) = ok;
    }
    const int orow = q0 + wave * 16 + lr;
#pragma unroll
    for (int tt = 0; tt < 4; tt++) {
      bf16x8 ov = *(const bf16x8*)(Bw + lr * 136 + lp * 32 + tt * 8);
      *(bf16x8*)(ob + ((size_t)(b * Q_ + orow) * HQ_ + h) * D_ + lp * 32 + tt * 8) = ov;
    }
  }
}

// ---------------- launcher ----------------
extern "C" void kernel_launch(void* const* d_in, const int* in_sizes, int n_in,
                              void* d_out, int out_size, void* d_ws, size_t ws_size,
                              hipStream_t stream) {
  const int*   positions = (const int*)  d_in[0];
  const float* hidden    = (const float*)d_in[1];
  const float* wqkv      = (const float*)d_in[4];
  const float* wo        = (const float*)d_in[5];
  const float* qnw       = (const float*)d_in[6];
  const float* knw       = (const float*)d_in[7];
  char* ws = (char*)d_ws;
  u16*   hid_bf  = (u16*)(ws);                     // 16,777,216
  u16*   wqkv_bf = (u16*)(ws + 16777216);          // 12,582,912
  u16*   wo_bf   = (u16*)(ws + 29360128);          //  8,388,608
  u16*   q_bf    = (u16*)(ws + 37748736);          // 16,777,216
  u16*   k_bf    = (u16*)(ws + 54525952);          //  4,194,304
  u16*   vt_bf   = (u16*)(ws + 58720256);          //  4,194,304
  float* rope    = (float*)(ws + 62914560);        //  2,097,152
  u16*   attn_bf = hid_bf;                         // alias: dead after gemm_qkv

  cvt_all<<<19456, 256, 0, stream>>>(hidden, wqkv, wo, positions,
                                     hid_bf, wqkv_bf, wo_bf, rope);
  gemm_qkv<<<dim3(32, 24), 256, 0, stream>>>(hid_bf, wqkv_bf, rope, qnw, knw,
                                             q_bf, k_bf, vt_bf);
  attn_fwd<<<dim3(16, 16, 2), 256, 0, stream>>>(q_bf, k_bf, vt_bf, attn_bf);
  gemm_bt<<<dim3(32, 16), 256, 0, stream>>>(attn_bf, wo_bf, (float*)d_out, 4096, 2048, 2048);
}